// Round 2
// baseline (176.097 us; speedup 1.0000x reference)
//
#include <hip/hip_runtime.h>
#include <math.h>

typedef unsigned short u16;
typedef unsigned int u32;
typedef __attribute__((ext_vector_type(2))) __fp16 half2;
typedef __attribute__((ext_vector_type(8))) __fp16 half8;
typedef __attribute__((ext_vector_type(16))) float floatx16;

constexpr int CB = 8;      // batch
constexpr int CS = 2048;   // seq
constexpr int CE = 256;    // emb
constexpr int CH = 8;      // heads
constexpr int CD = 32;     // head dim
constexpr float CLN_EPS = 1e-5f;
// scores get exp2 via poly; fold scale * log2(e) into Q at projection time
constexpr float QSC = 0.0625f * 1.44269504088896341f;

constexpr int QP = 40;    // lds pitch (shorts) for K tiles (proven low-conflict)
constexpr int VP = 72;    // lds pitch (shorts) for V^T tiles (proven low-conflict)
constexpr int XP = 268;   // lds pitch (shorts) for x tile (max 2-way banks)
constexpr int RST = 4104; // revg8 per-(h,p) stride in shorts

__device__ inline u32 fbits(float f) { union { float f; u32 u; } c; c.f = f; return c.u; }
// pack two f32 -> two f16 in one dword (v_cvt_pkrtz_f16_f32, 1 inst; low half = a)
__device__ inline u32 pkrtz(float a, float b) {
  half2 h = __builtin_amdgcn_cvt_pkrtz(a, b);
  union { half2 h; u32 u; } c; c.h = h; return c.u;
}
__device__ inline u16 h1(float a) {
  union { __fp16 h; u16 u; } c; c.h = (__fp16)a; return c.u;
}
__device__ inline half8 ldh8(const u16* p) {
  union { uint4 q; half8 v; } c; c.q = *(const uint4*)p; return c.v;
}

// v_permlane32_swap_b32: a' = {a.lo32, b.lo32}, b' = {a.hi32, b.hi32}
#if __has_builtin(__builtin_amdgcn_permlane32_swap)
__device__ inline void swap32(u32& a, u32& b) {
  typedef __attribute__((ext_vector_type(2))) unsigned int uint2v;
  uint2v r = __builtin_amdgcn_permlane32_swap(a, b, false, false);
  a = r[0]; b = r[1];
}
#else
__device__ inline void swap32(u32& a, u32& b) {
  int hi = (threadIdx.x >> 5) & 1;
  u32 sa = (u32)__shfl_xor((int)a, 32);
  u32 sb = (u32)__shfl_xor((int)b, 32);
  u32 na = hi ? sb : a;
  u32 nb = hi ? b : sa;
  a = na; b = nb;
}
#endif

// ------------- prep (merged): W f32->f16  +  reversed bias 8-shift copies (f16) -------
__global__ __launch_bounds__(256) void prep_kernel(
    const float* __restrict__ Wq, const float* __restrict__ Wk,
    const float* __restrict__ Wv, const float* __restrict__ table,
    u16* __restrict__ Wb, u16* __restrict__ revg) {
  int gid = blockIdx.x * 256 + threadIdx.x;
  if (gid < 49152) {                           // W convert: 3 * 16384 float4s
    int which = gid >> 14;
    int off = (gid & 16383) * 4;
    const float* W = (which == 0) ? Wq : (which == 1) ? Wk : Wv;
    float4 f = *(const float4*)&W[off];
    uint2 o; o.x = pkrtz(f.x, f.y); o.y = pkrtz(f.z, f.w);
    *(uint2*)&Wb[(size_t)which * CE * CE + off] = o;
  } else {
    int gid2 = gid - 49152;                    // 64*513 = 32832 uint4 groups
    if (gid2 >= 64 * 513) return;
    int g = gid2 / 513;                        // h*8 + p
    int j0 = (gid2 - g * 513) * 8;
    int h = g >> 3, p = g & 7;
    u16 vals[8];
#pragma unroll
    for (int t = 0; t < 8; ++t) {
      int src = 4094 - (j0 + t + p);
      vals[t] = (src >= 0) ? h1(table[(size_t)src * CH + h]) : (u16)0;
    }
    *(uint4*)&revg[(size_t)g * RST + j0] = *(uint4*)vals;
  }
}

// ---------------- QKV: y = x @ W.T via f16 MFMA (A = W, B = x^T) ----------------
// grid (256, 3): block = 64 s-rows x ALL 256 features of one matrix (q/k/v).
// x tile staged to LDS ONCE per block; W f16 streamed from L2 in k-loop.
// C layout: lane = s, regs = features. q,k f16 [bh][s][d] (q pre-scaled);
// v TRANSPOSED f16 [bh][d][s].
__global__ __launch_bounds__(256, 4) void qkv_mfma_kernel(
    const float* __restrict__ x, const u16* __restrict__ Wb,
    u16* __restrict__ qb, u16* __restrict__ kb, u16* __restrict__ vb) {
  __shared__ __attribute__((aligned(16))) u16 Xs[64 * XP];
  const int m0 = blockIdx.x * 64;
  const int which = blockIdx.y;                // 0=q 1=k 2=v
  const int tid = threadIdx.x;
  const int lane = tid & 63, wv = tid >> 6;
  const int lm = lane & 31, lg = lane >> 5;

  // stage x tile 64x256 f32 -> f16 (once per block)
#pragma unroll
  for (int it = 0; it < 16; ++it) {
    int c = tid + 256 * it;                    // 0..4095 float4-units
    int row = c >> 6, f4 = c & 63;
    float4 f = *(const float4*)&x[(size_t)(m0 + row) * CE + f4 * 4];
    uint2 o; o.x = pkrtz(f.x, f.y); o.y = pkrtz(f.z, f.w);
    *(uint2*)&Xs[row * XP + f4 * 4] = o;
  }
  __syncthreads();

  const u16* Wsrc = Wb + (size_t)which * CE * CE;

#pragma unroll
  for (int r = 0; r < 2; ++r) {
    const int F = wv * 32 + r * 128;           // this wave's feature tile (= head F>>5)
    floatx16 acc0, acc1;                       // m-subtiles: s rows 0-31, 32-63
#pragma unroll
    for (int i = 0; i < 16; ++i) { acc0[i] = 0.f; acc1[i] = 0.f; }
#pragma unroll
    for (int kt = 0; kt < 16; ++kt) {
      half8 wfr = ldh8(&Wsrc[(size_t)(F + lm) * CE + kt * 16 + lg * 8]);  // L2-hot
      half8 b0 = ldh8(&Xs[lm * XP + kt * 16 + lg * 8]);
      half8 b1 = ldh8(&Xs[(32 + lm) * XP + kt * 16 + lg * 8]);
      acc0 = __builtin_amdgcn_mfma_f32_32x32x16_f16(wfr, b0, acc0, 0, 0, 0);
      acc1 = __builtin_amdgcn_mfma_f32_32x32x16_f16(wfr, b1, acc1, 0, 0, 0);
    }
    const int hh = F >> 5;
#pragma unroll
    for (int ms = 0; ms < 2; ++ms) {
      floatx16& acc = ms ? acc1 : acc0;
      const int sg = m0 + ms * 32 + lm;
      const int bI = sg >> 11, sI = sg & (CS - 1);
      if (which < 2) {
        u16* dst = which ? kb : qb;
        float scl = which ? 1.0f : QSC;
        u32 D[8];
#pragma unroll
        for (int g = 0; g < 8; ++g)
          D[g] = pkrtz(acc[2 * g] * scl, acc[2 * g + 1] * scl);
        swap32(D[0], D[2]); swap32(D[1], D[3]);
        swap32(D[4], D[6]); swap32(D[5], D[7]);
        size_t base = (((size_t)bI * CH + hh) * CS + sI) * CD;
        uint4 U0; U0.x = D[0]; U0.y = D[1]; U0.z = D[2]; U0.w = D[3];
        uint4 U1; U1.x = D[4]; U1.y = D[5]; U1.z = D[6]; U1.w = D[7];
        *(uint4*)&dst[base + 8 * lg] = U0;
        *(uint4*)&dst[base + 16 + 8 * lg] = U1;
      } else {
        // v transposed [bh][d][s]: lane lm = s consecutive -> coalesced b16 stores
#pragma unroll
        for (int rg = 0; rg < 16; ++rg) {
          int d = (rg & 3) + 8 * (rg >> 2) + 4 * lg;
          vb[(((size_t)bI * CH + hh) * CD + d) * CS + sI] = h1(acc[rg]);
        }
      }
    }
  }
}

// ---------------- attention v3: LDS dataflow + XCD swizzle + 2-tile stages ----------
// R1 lesson: barrier-free direct-global regressed (latency-bound, occupancy fell);
// the LDS staging is load-bearing (4x traffic amortization + short-latency ds_read).
// Kept from R1: the L2/L1 co-residency swizzle (FETCH 71.6 -> 12.6 MB proven).
// New vs v1: (a) two 64-k tiles per __syncthreads (16 barriers instead of 32),
// (b) persistent zero C-operand for score MFMAs (kills 32 v_mov per tile),
// (c) s_setprio(1) around MFMA clusters (waves in different blocks progress
// independently -> phase diversity for the CU scheduler).
__global__ __launch_bounds__(256, 4) void attn_mfma_kernel(
    const u16* __restrict__ qm, const u16* __restrict__ km,
    const u16* __restrict__ vm, const u16* __restrict__ revg,
    float* __restrict__ out) {
  __shared__ __attribute__((aligned(16))) u16 Ks[2][2][64 * QP];
  __shared__ __attribute__((aligned(16))) u16 Vt[2][2][32 * VP];

  const int id = blockIdx.x;
  const int bh = id & 63;                 // XCD gets one h; co-resident blocks share bh
  const int q0 = (id >> 6) * 128;         // 16 q-blocks of 128 rows
  const int b = bh >> 3, h = bh & 7;
  const int tid = threadIdx.x;
  const int lane = tid & 63, wv = tid >> 6;
  const int lm = lane & 31, lg = lane >> 5;
  const u16* qbp = qm + (size_t)bh * CS * CD;
  const u16* kbp = km + (size_t)bh * CS * CD;
  const u16* vbp = vm + (size_t)bh * CD * CS;   // transposed [d][s]

  // Q B-fragments straight from global (once per block)
  const int qrow = wv * 32 + lm;
  const u16* qp = qbp + (size_t)(q0 + qrow) * CD;
  half8 qa0 = ldh8(qp + lg * 8);
  half8 qa1 = ldh8(qp + 16 + lg * 8);

  // per-lane bias stream pointer (X % 8 is loop-invariant)
  const int Xb = 2047 - q0 - qrow + lg * 8;
  const int pp = Xb & 7;
  const u16* bp = revg + (size_t)(h * 8 + pp) * RST + (Xb - pp);

  // register prefetch of K/V stage 0 (two 64-k tiles)
  const int krow = tid >> 2, kch = tid & 3;      // K: 64 rows x 4 chunks
  const int vrow = tid >> 3, vch = tid & 7;      // V^T: 32 rows x 8 chunks
  uint4 kr0 = *(const uint4*)&kbp[(size_t)krow * CD + kch * 8];
  uint4 kr1 = *(const uint4*)&kbp[(size_t)(64 + krow) * CD + kch * 8];
  uint4 vr0 = *(const uint4*)&vbp[(size_t)vrow * CS + vch * 8];
  uint4 vr1 = *(const uint4*)&vbp[(size_t)vrow * CS + 64 + vch * 8];

  // exp2 poly coefficients (degree 3, |x|<=0.36, err ~5e-5)
  const half2 PC3 = {(__fp16)0.0558022f, (__fp16)0.0558022f};
  const half2 PC2 = {(__fp16)0.2401997f, (__fp16)0.2401997f};
  const half2 PC1 = {(__fp16)0.6931472f, (__fp16)0.6931472f};
  const half2 PC0 = {(__fp16)1.0f, (__fp16)1.0f};

  // persistent zero vector: C-operand for the first mfma of each score chain
  floatx16 zf;
#pragma unroll
  for (int i = 0; i < 16; ++i) zf[i] = 0.f;
  floatx16 acc_e = zf, acc_b = zf;
  float l = 0.f;

  for (int s0 = 0; s0 < CS; s0 += 128) {
    const int p = (s0 >> 7) & 1;
    *(uint4*)&Ks[p][0][krow * QP + kch * 8] = kr0;
    *(uint4*)&Ks[p][1][krow * QP + kch * 8] = kr1;
    *(uint4*)&Vt[p][0][vrow * VP + vch * 8] = vr0;
    *(uint4*)&Vt[p][1][vrow * VP + vch * 8] = vr1;
    if (s0 + 128 < CS) {
      kr0 = *(const uint4*)&kbp[(size_t)(s0 + 128 + krow) * CD + kch * 8];
      kr1 = *(const uint4*)&kbp[(size_t)(s0 + 192 + krow) * CD + kch * 8];
      vr0 = *(const uint4*)&vbp[(size_t)vrow * CS + (s0 + 128) + vch * 8];
      vr1 = *(const uint4*)&vbp[(size_t)vrow * CS + (s0 + 192) + vch * 8];
    }
    __syncthreads();   // single barrier per 128-k stage (double buffer covers WAR)

#pragma unroll
    for (int t = 0; t < 2; ++t) {
      const int k0 = s0 + t * 64;
      // bias fragments for this tile (L2-hot; ~400 cyc of score work hides latency)
      uint4 bu0 = *(const uint4*)&bp[k0];
      uint4 bu1 = *(const uint4*)&bp[k0 + 16];
      uint4 bu2 = *(const uint4*)&bp[k0 + 32];
      uint4 bu3 = *(const uint4*)&bp[k0 + 48];

      // ---- S^T = K·Q^T: two 32k x 32q tiles (lane = q, regs = k) ----
      half8 a00 = ldh8(&Ks[p][t][lm * QP + lg * 8]);
      half8 a01 = ldh8(&Ks[p][t][lm * QP + 16 + lg * 8]);
      half8 a10 = ldh8(&Ks[p][t][(32 + lm) * QP + lg * 8]);
      half8 a11 = ldh8(&Ks[p][t][(32 + lm) * QP + 16 + lg * 8]);
      __builtin_amdgcn_s_setprio(1);
      floatx16 sc0 = __builtin_amdgcn_mfma_f32_32x32x16_f16(a00, qa0, zf, 0, 0, 0);
      sc0 = __builtin_amdgcn_mfma_f32_32x32x16_f16(a01, qa1, sc0, 0, 0, 0);
      floatx16 sc1 = __builtin_amdgcn_mfma_f32_32x32x16_f16(a10, qa0, zf, 0, 0, 0);
      sc1 = __builtin_amdgcn_mfma_f32_32x32x16_f16(a11, qa1, sc1, 0, 0, 0);
      __builtin_amdgcn_s_setprio(0);

      half2 lacc = {(__fp16)0.0f, (__fp16)0.0f};   // per-tile packed l accumulator
#pragma unroll
      for (int ct = 0; ct < 2; ++ct) {
        floatx16& sc = ct ? sc1 : sc0;
        // p = 2^s via packed-f16 poly; pack pairs (consecutive k per dword)
        u32 P[8];
#pragma unroll
        for (int g = 0; g < 8; ++g) {
          half2 xv = __builtin_amdgcn_cvt_pkrtz(sc[2 * g], sc[2 * g + 1]);
          half2 r = __builtin_elementwise_fma(PC3, xv, PC2);
          r = __builtin_elementwise_fma(r, xv, PC1);
          r = __builtin_elementwise_fma(r, xv, PC0);
          lacc += r;
          union { half2 hh; u32 u; } cc; cc.hh = r;
          P[g] = cc.u;
        }
        // C-layout -> B-operand layout: half exchange via permlane32_swap
        swap32(P[0], P[2]); swap32(P[1], P[3]);
        swap32(P[4], P[6]); swap32(P[5], P[7]);
        union { u32 u[4]; half8 v; } B0, B1;
        B0.u[0] = P[0]; B0.u[1] = P[1]; B0.u[2] = P[2]; B0.u[3] = P[3];
        B1.u[0] = P[4]; B1.u[1] = P[5]; B1.u[2] = P[6]; B1.u[3] = P[7];
        // A = V^T chunks (lane = d), contraction k
        half8 va0 = ldh8(&Vt[p][t][lm * VP + ct * 32 + lg * 8]);
        half8 va1 = ldh8(&Vt[p][t][lm * VP + ct * 32 + 16 + lg * 8]);
        union { uint4 q; half8 v; } Bb0, Bb1;
        Bb0.q = ct ? bu2 : bu0;
        Bb1.q = ct ? bu3 : bu1;
        __builtin_amdgcn_s_setprio(1);
        acc_e = __builtin_amdgcn_mfma_f32_32x32x16_f16(va0, B0.v, acc_e, 0, 0, 0);
        acc_e = __builtin_amdgcn_mfma_f32_32x32x16_f16(va1, B1.v, acc_e, 0, 0, 0);
        acc_b = __builtin_amdgcn_mfma_f32_32x32x16_f16(va0, Bb0.v, acc_b, 0, 0, 0);
        acc_b = __builtin_amdgcn_mfma_f32_32x32x16_f16(va1, Bb1.v, acc_b, 0, 0, 0);
        __builtin_amdgcn_s_setprio(0);
      }
      // flush packed l (max ~41 per tile -> f16-safe) into f32 master accumulator
      l += (float)lacc[0] + (float)lacc[1];
    }
  }

  // l: the two lg-halves hold complementary halves of row q's sum
  l += __shfl_xor(l, 32);
  float rl = __builtin_amdgcn_rcpf(l);
  // O^T C-layout: lane = q, regs = d in groups of 4 -> float4 stores
  size_t ob = ((size_t)b * CS + q0 + qrow) * CE + h * CD;
#pragma unroll
  for (int g = 0; g < 4; ++g) {
    float4 r4;
    r4.x = acc_e[4 * g + 0] * rl + acc_b[4 * g + 0];
    r4.y = acc_e[4 * g + 1] * rl + acc_b[4 * g + 1];
    r4.z = acc_e[4 * g + 2] * rl + acc_b[4 * g + 2];
    r4.w = acc_e[4 * g + 3] * rl + acc_b[4 * g + 3];
    *(float4*)&out[ob + 8 * g + 4 * lg] = r4;
  }
}

// ---------------- LayerNorm over E: one wave per row, float4 per lane ----------------
__global__ __launch_bounds__(256) void ln_kernel(float* __restrict__ io,
                                                 const float* __restrict__ gamma,
                                                 const float* __restrict__ beta) {
  int tid = threadIdx.x;
  size_t row = (size_t)blockIdx.x * 4 + (tid >> 6);
  int c = (tid & 63) * 4;
  float4 v = *(const float4*)&io[row * CE + c];
  float s1 = v.x + v.y + v.z + v.w;
  float s2 = v.x * v.x + v.y * v.y + v.z * v.z + v.w * v.w;
#pragma unroll
  for (int off = 1; off < 64; off <<= 1) {
    s1 += __shfl_xor(s1, off);
    s2 += __shfl_xor(s2, off);
  }
  float mu = s1 * (1.0f / CE);
  float var = s2 * (1.0f / CE) - mu * mu;
  float rs = rsqrtf(var + CLN_EPS);
  float4 g = *(const float4*)&gamma[c];
  float4 be = *(const float4*)&beta[c];
  float4 o;
  o.x = (v.x - mu) * rs * g.x + be.x;
  o.y = (v.y - mu) * rs * g.y + be.y;
  o.z = (v.z - mu) * rs * g.z + be.z;
  o.w = (v.w - mu) * rs * g.w + be.w;
  *(float4*)&io[row * CE + c] = o;
}

extern "C" void kernel_launch(void* const* d_in, const int* in_sizes, int n_in,
                              void* d_out, int out_size, void* d_ws, size_t ws_size,
                              hipStream_t stream) {
  (void)in_sizes; (void)n_in; (void)out_size; (void)ws_size;
  const float* x          = (const float*)d_in[0];
  const float* Wq         = (const float*)d_in[1];
  const float* Wk         = (const float*)d_in[2];
  const float* Wv         = (const float*)d_in[3];
  const float* bias_table = (const float*)d_in[4];
  const float* gamma      = (const float*)d_in[5];
  const float* beta       = (const float*)d_in[6];
  float* out = (float*)d_out;

  // ws layout (u16): Wb[3*256*256] | qb | kb | vb(transposed) | revg8[64*4104]  ~26.2 MB
  u16* ws = (u16*)d_ws;
  u16* Wb = ws;
  u16* qb = Wb + 3 * CE * CE;
  u16* kb = qb + (size_t)CB * CH * CS * CD;
  u16* vb = kb + (size_t)CB * CH * CS * CD;
  u16* revg = vb + (size_t)CB * CH * CS * CD;

  prep_kernel<<<dim3(321), dim3(256), 0, stream>>>(Wq, Wk, Wv, bias_table, Wb, revg);
  qkv_mfma_kernel<<<dim3(256, 3), dim3(256), 0, stream>>>(x, Wb, qb, kb, vb);
  attn_mfma_kernel<<<dim3(1024), dim3(256), 0, stream>>>(qb, kb, vb, revg, out);
  ln_kernel<<<dim3(CB * CS / 4), dim3(256), 0, stream>>>(out, gamma, beta);
}